// Round 1
// baseline (79.093 us; speedup 1.0000x reference)
//
#include <hip/hip_runtime.h>

// bg: (1, 4, 32, 32, 32, 16) f32  -> (n, c, h, w, d, up)
// gm: (1, 1, 128, 128, 128) f32   -> (n, 1, gh, gw, gd)
// out: (1, 4, 128, 128, 128) f32  -> (n, c, gh, gw, gd)

#define GH 128
#define GW 128
#define GD 128
#define GRID_H 32
#define GRID_W 32
#define GRID_D 32
#define UP 16
#define NCH 4
#define CH_STRIDE (GRID_H * GRID_W * GRID_D * UP)   // 524288
#define TOTAL (GH * GW * GD)                        // 2097152

__global__ __launch_bounds__(256) void bgrid_slice_kernel(
    const float* __restrict__ bg,
    const float* __restrict__ gm,
    float* __restrict__ out)
{
    int idx = blockIdx.x * 256 + threadIdx.x;
    if (idx >= TOTAL) return;

    int k = idx & (GD - 1);
    int j = (idx >> 7) & (GW - 1);
    int i = idx >> 14;

    // voxel-space coords: arange(128) * 31/127 -> always within [0, 31]
    const float s = 31.0f / 127.0f;
    float xf = (float)i * s;
    float yf = (float)j * s;
    float zf = (float)k * s;

    int x0 = (int)xf; float fx = xf - (float)x0; int x1 = min(x0 + 1, GRID_H - 1);
    int y0 = (int)yf; float fy = yf - (float)y0; int y1 = min(y0 + 1, GRID_W - 1);
    int z0 = (int)zf; float fz = zf - (float)z0; int z1 = min(z0 + 1, GRID_D - 1);

    float t = gm[idx] * (float)(UP - 1);
    t = fminf(fmaxf(t, 0.0f), (float)(UP - 1));
    int t0 = (int)t;
    t0 = min(t0, UP - 1);
    float ft = t - (float)t0;
    int t1 = min(t0 + 1, UP - 1);
    float omft = 1.0f - ft;

    float wxs[2] = {1.0f - fx, fx};
    int   xs[2]  = {x0, x1};
    float wys[2] = {1.0f - fy, fy};
    int   ys[2]  = {y0, y1};
    float wzs[2] = {1.0f - fz, fz};
    int   zs[2]  = {z0, z1};

    float acc0 = 0.f, acc1 = 0.f, acc2 = 0.f, acc3 = 0.f;

    #pragma unroll
    for (int a = 0; a < 2; ++a) {
        #pragma unroll
        for (int b = 0; b < 2; ++b) {
            #pragma unroll
            for (int d2 = 0; d2 < 2; ++d2) {
                float w = wxs[a] * wys[b] * wzs[d2];
                int base = ((xs[a] * GRID_W + ys[b]) * GRID_D + zs[d2]) * UP;
                const float* p0 = bg + base;
                float v0 = p0[t0] * omft + p0[t1] * ft;
                const float* p1 = p0 + CH_STRIDE;
                float v1 = p1[t0] * omft + p1[t1] * ft;
                const float* p2 = p1 + CH_STRIDE;
                float v2 = p2[t0] * omft + p2[t1] * ft;
                const float* p3 = p2 + CH_STRIDE;
                float v3 = p3[t0] * omft + p3[t1] * ft;
                acc0 += w * v0;
                acc1 += w * v1;
                acc2 += w * v2;
                acc3 += w * v3;
            }
        }
    }

    out[idx]                  = acc0;
    out[idx + TOTAL]          = acc1;
    out[idx + 2 * TOTAL]      = acc2;
    out[idx + 3 * TOTAL]      = acc3;
}

extern "C" void kernel_launch(void* const* d_in, const int* in_sizes, int n_in,
                              void* d_out, int out_size, void* d_ws, size_t ws_size,
                              hipStream_t stream) {
    const float* bg = (const float*)d_in[0];
    const float* gm = (const float*)d_in[1];
    float* out = (float*)d_out;

    dim3 grid(TOTAL / 256);
    dim3 block(256);
    bgrid_slice_kernel<<<grid, block, 0, stream>>>(bg, gm, out);
}

// Round 2
// 22.068 us; speedup vs baseline: 3.5840x; 3.5840x over previous
//
#include <hip/hip_runtime.h>

// bg: (1, 4, 32, 32, 32, 16) f32  -> (n, c, h, w, d, up)
// gm: (1, 1, 128, 128, 128) f32
// out: (1, 4, 128, 128, 128) f32
//
// Tile: 4(i) x 4(j) x 32(k) output voxels per 512-thread block.
// Needed grid nodes per tile: x in [x_base, x_base+2] (3), y likewise (3),
// z in [z_base, z_base+9] (10)  -> 90 nodes * 4ch * 16up = 23KB staged in LDS.
// LDS layout per node: [16 t][4 ch] floats (so t-interp is two ds_read_b128),
// node stride padded 64->68 dwords to spread banks (t0<16 would use half).

#define S_ (31.0f / 127.0f)
#define CH_STRIDE 524288   // 32*32*32*16
#define TOTAL 2097152      // 128^3

#define NX 3
#define NY 3
#define NZ 10
#define NNODES (NX * NY * NZ)        // 90
#define NODE_STRIDE 68               // dwords: 64 data + 4 pad
#define LDS_DWORDS (NNODES * NODE_STRIDE)

__global__ __launch_bounds__(512) void bgrid_slice_lds(
    const float* __restrict__ bg,
    const float* __restrict__ gm,
    float* __restrict__ out)
{
    __shared__ float lds[LDS_DWORDS];

    const int tid = threadIdx.x;
    const int b = blockIdx.x;
    const int bk = b & 3;
    const int bj = (b >> 2) & 31;
    const int bi = b >> 7;

    const int i0 = bi * 4, j0 = bj * 4, k0 = bk * 32;
    const int x_base = (int)((float)i0 * S_);
    const int y_base = (int)((float)j0 * S_);
    const int z_base = (int)((float)k0 * S_);

    // ---- stage bg tile into LDS (transpose row [16t] -> [t][c]) ----
    // q indexes float4s: per node 4ch*4seg = 16; total 90*16 = 1440.
    for (int q = tid; q < NNODES * 16; q += 512) {
        int node = q >> 4;
        int ch   = (q >> 2) & 3;
        int seg  = q & 3;
        int a   = node / 30;
        int rem = node - a * 30;
        int bb  = rem / 10;
        int cz  = rem - bb * 10;
        int gx = min(x_base + a, 31);
        int gy = min(y_base + bb, 31);
        int gz = min(z_base + cz, 31);
        const float4 v = *(const float4*)(bg + ch * CH_STRIDE +
                                          (((gx * 32 + gy) * 32 + gz) << 4) + (seg << 2));
        int d = node * NODE_STRIDE + seg * 16 + ch;   // dword index; t = seg*4+dt at d+4*dt
        lds[d]      = v.x;
        lds[d + 4]  = v.y;
        lds[d + 8]  = v.z;
        lds[d + 12] = v.w;
    }
    __syncthreads();

    // ---- per-voxel quadrilinear interpolation from LDS ----
    const int lk = tid & 31;
    const int lj = (tid >> 5) & 3;
    const int li = tid >> 7;
    const int i = i0 + li, j = j0 + lj, k = k0 + lk;

    float xf = fminf((float)i * S_, 31.0f);
    float yf = fminf((float)j * S_, 31.0f);
    float zf = fminf((float)k * S_, 31.0f);
    int x0g = (int)xf; float fx = xf - (float)x0g;
    int y0g = (int)yf; float fy = yf - (float)y0g;
    int z0g = (int)zf; float fz = zf - (float)z0g;

    int xi0 = x0g - x_base, xi1 = min(x0g + 1, 31) - x_base;
    int yi0 = y0g - y_base, yi1 = min(y0g + 1, 31) - y_base;
    int zi0 = z0g - z_base, zi1 = min(z0g + 1, 31) - z_base;

    const int idx = (i << 14) | (j << 7) | k;
    float t = gm[idx] * 15.0f;
    t = fminf(fmaxf(t, 0.0f), 15.0f);
    int t0 = min((int)t, 14);           // lerp(p14,p15,1) == lerp(p15,p15,0)
    float ft = t - (float)t0;

    const int ax0 = xi0 * (NY * NZ * NODE_STRIDE);
    const int ax1 = xi1 * (NY * NZ * NODE_STRIDE);
    const int by0 = yi0 * (NZ * NODE_STRIDE);
    const int by1 = yi1 * (NZ * NODE_STRIDE);
    const int cz0 = zi0 * NODE_STRIDE;
    const int cz1 = zi1 * NODE_STRIDE;
    const int tt = t0 * 4;

    const float wx1 = fx, wx0 = 1.0f - fx;
    const float wy1 = fy, wy0 = 1.0f - fy;
    const float wz1 = fz, wz0 = 1.0f - fz;
    const float wxy00 = wx0 * wy0, wxy01 = wx0 * wy1;
    const float wxy10 = wx1 * wy0, wxy11 = wx1 * wy1;

    float acc0 = 0.f, acc1 = 0.f, acc2 = 0.f, acc3 = 0.f;

#define CORNER(AX, BY, CZ, W)                                        \
    {                                                                \
        const int base = (AX) + (BY) + (CZ) + tt;                    \
        const float4 p0 = *(const float4*)&lds[base];                \
        const float4 p1 = *(const float4*)&lds[base + 4];            \
        const float w = (W);                                         \
        acc0 = fmaf(w, fmaf(ft, p1.x - p0.x, p0.x), acc0);           \
        acc1 = fmaf(w, fmaf(ft, p1.y - p0.y, p0.y), acc1);           \
        acc2 = fmaf(w, fmaf(ft, p1.z - p0.z, p0.z), acc2);           \
        acc3 = fmaf(w, fmaf(ft, p1.w - p0.w, p0.w), acc3);           \
    }

    CORNER(ax0, by0, cz0, wxy00 * wz0)
    CORNER(ax0, by0, cz1, wxy00 * wz1)
    CORNER(ax0, by1, cz0, wxy01 * wz0)
    CORNER(ax0, by1, cz1, wxy01 * wz1)
    CORNER(ax1, by0, cz0, wxy10 * wz0)
    CORNER(ax1, by0, cz1, wxy10 * wz1)
    CORNER(ax1, by1, cz0, wxy11 * wz0)
    CORNER(ax1, by1, cz1, wxy11 * wz1)
#undef CORNER

    out[idx]             = acc0;
    out[idx + TOTAL]     = acc1;
    out[idx + 2 * TOTAL] = acc2;
    out[idx + 3 * TOTAL] = acc3;
}

extern "C" void kernel_launch(void* const* d_in, const int* in_sizes, int n_in,
                              void* d_out, int out_size, void* d_ws, size_t ws_size,
                              hipStream_t stream) {
    const float* bg = (const float*)d_in[0];
    const float* gm = (const float*)d_in[1];
    float* out = (float*)d_out;

    dim3 grid(4096);   // (128/4) * (128/4) * (128/32)
    dim3 block(512);
    bgrid_slice_lds<<<grid, block, 0, stream>>>(bg, gm, out);
}